// Round 2
// baseline (455.430 us; speedup 1.0000x reference)
//
#include <hip/hip_runtime.h>

// Problem constants (x: (16,3,512,512) f32, PATCH=16, STRIDE=8, k=8)
#define BB      16
#define CH      3
#define HH      512
#define WW      512
#define NH      63
#define NW      63
#define NN      3969            // NH*NW
#define FDIM    768             // CH*16*16
#define EDGES   31752           // NN*8

#define PATCHES_ELEMS  (BB * NN * FDIM)   // 48771072
#define POS_ELEMS      (BB * NN * 2)      // 127008

#define F16            (FDIM / 16)        // 48 threads' worth per (b,n), 16 floats each
#define PATCH_THREADS  (BB * NN * F16)    // 3048192
#define PATCH_BLOCKS   (PATCH_THREADS / 256)   // 11907 (exact)
#define PE_THREADS     (BB * NN)          // 63504
#define PE_BLOCKS      ((PE_THREADS + 255) / 256)  // 249

typedef float  f4 __attribute__((ext_vector_type(4)));
typedef float  f2 __attribute__((ext_vector_type(2)));

// ---------------------------------------------------------------------------
// One fused kernel.
//  blocks [0, PATCH_BLOCKS)          : patches gather, 16 floats (one patch
//                                      row of one channel) per thread.
//                                      64B contiguous read, 64B contiguous
//                                      write, nontemporal stores.
//  blocks [PATCH_BLOCKS, +PE_BLOCKS) : one thread per (b,n) -> positions
//                                      float2 + 8-NN edge rows (4x f4 stores,
//                                      coalesced across lanes).
// ---------------------------------------------------------------------------
__global__ __launch_bounds__(256) void fused_kernel(const float* __restrict__ x,
                                                    float* __restrict__ out) {
    unsigned bid = blockIdx.x;

    if (bid < PATCH_BLOCKS) {
        unsigned t    = bid * 256u + threadIdx.x;   // [0, PATCH_THREADS)
        unsigned f16  = t % F16;                    // which (c,di) row
        unsigned rest = t / F16;
        unsigned n    = rest % NN;
        unsigned b    = rest / NN;
        unsigned c    = f16 >> 4;                   // 0..2
        unsigned di   = f16 & 15;
        unsigned i    = n / NW;
        unsigned j    = n - i * NW;

        const float* src = x + ((size_t)((b * CH + c) * HH + i * 8u + di) * WW + j * 8u);
        f4 v0 = *reinterpret_cast<const f4*>(src + 0);
        f4 v1 = *reinterpret_cast<const f4*>(src + 4);
        f4 v2 = *reinterpret_cast<const f4*>(src + 8);
        f4 v3 = *reinterpret_cast<const f4*>(src + 12);

        float* dst = out + (size_t)t * 16;
        __builtin_nontemporal_store(v0, reinterpret_cast<f4*>(dst + 0));
        __builtin_nontemporal_store(v1, reinterpret_cast<f4*>(dst + 4));
        __builtin_nontemporal_store(v2, reinterpret_cast<f4*>(dst + 8));
        __builtin_nontemporal_store(v3, reinterpret_cast<f4*>(dst + 12));
    } else {
        unsigned g = (bid - PATCH_BLOCKS) * 256u + threadIdx.x;
        if (g >= PE_THREADS) return;
        unsigned n = g % NN;                        // lanes contiguous in n
        unsigned b = g / NN;
        int i = (int)(n / NW);
        int j = (int)(n - (unsigned)i * NW);

        // positions
        f2 p; p.x = (float)i; p.y = (float)j;
        __builtin_nontemporal_store(
            p, reinterpret_cast<f2*>(out + PATCHES_ELEMS + (size_t)(b * NN + n) * 2));

        // 8-NN on the 63x63 grid: the 9 best (incl. self) of top_k(-d2, 9)
        // always lie in the clipped 5x5 window; key = (d2<<12)|idx reproduces
        // top_k's exact ordering (ties -> lower index).
        unsigned best[9];
#pragma unroll
        for (int s = 0; s < 9; ++s) best[s] = 0xFFFFFFFFu;
        for (int di = -2; di <= 2; ++di) {
            int ni = i + di;
            if (ni < 0 || ni >= NH) continue;
            for (int dj = -2; dj <= 2; ++dj) {
                int nj = j + dj;
                if (nj < 0 || nj >= NW) continue;
                unsigned key = ((unsigned)(di * di + dj * dj) << 12)
                             | (unsigned)(ni * NW + nj);
#pragma unroll
                for (int s = 0; s < 9; ++s) {
                    if (key < best[s]) { unsigned tmp = best[s]; best[s] = key; key = tmp; }
                }
            }
        }

        float src_f = (float)n;
        f4 s4; s4.x = src_f; s4.y = src_f; s4.z = src_f; s4.w = src_f;
        f4 t0, t1;
        t0.x = (float)(best[1] & 0xFFFu); t0.y = (float)(best[2] & 0xFFFu);
        t0.z = (float)(best[3] & 0xFFFu); t0.w = (float)(best[4] & 0xFFFu);
        t1.x = (float)(best[5] & 0xFFFu); t1.y = (float)(best[6] & 0xFFFu);
        t1.z = (float)(best[7] & 0xFFFu); t1.w = (float)(best[8] & 0xFFFu);

        float* ebase = out + PATCHES_ELEMS + POS_ELEMS + (size_t)b * 2 * EDGES;
        __builtin_nontemporal_store(s4, reinterpret_cast<f4*>(ebase + (size_t)n * 8));
        __builtin_nontemporal_store(s4, reinterpret_cast<f4*>(ebase + (size_t)n * 8 + 4));
        __builtin_nontemporal_store(t0, reinterpret_cast<f4*>(ebase + EDGES + (size_t)n * 8));
        __builtin_nontemporal_store(t1, reinterpret_cast<f4*>(ebase + EDGES + (size_t)n * 8 + 4));
    }
}

extern "C" void kernel_launch(void* const* d_in, const int* in_sizes, int n_in,
                              void* d_out, int out_size, void* d_ws, size_t ws_size,
                              hipStream_t stream) {
    const float* x = (const float*)d_in[0];
    float* out     = (float*)d_out;
    fused_kernel<<<PATCH_BLOCKS + PE_BLOCKS, 256, 0, stream>>>(x, out);
}

// Round 3
// 252.864 us; speedup vs baseline: 1.8011x; 1.8011x over previous
//
#include <hip/hip_runtime.h>

// Problem constants (x: (16,3,512,512) f32, PATCH=16, STRIDE=8, k=8)
#define BB      16
#define CH      3
#define HH      512
#define WW      512
#define NH      63
#define NW      63
#define NN      3969            // NH*NW
#define FDIM    768             // CH*16*16
#define EDGES   31752           // NN*8

#define PATCHES_ELEMS  (BB * NN * FDIM)   // 48771072
#define POS_ELEMS      (BB * NN * 2)      // 127008

#define F4             (FDIM / 4)              // 192 float4 per (b,n)
#define TOTAL_G        (BB * NN * F4)          // 12192768 float4s
#define PATCH_BLOCKS   (TOTAL_G / 256)         // 47628 (exact)
#define PE_THREADS     (BB * NN)               // 63504
#define PE_BLOCKS      ((PE_THREADS + 255) / 256)  // 249

typedef float  f4 __attribute__((ext_vector_type(4)));
typedef float  f2 __attribute__((ext_vector_type(2)));

// ---------------------------------------------------------------------------
// One fused kernel.
//  blocks [0, PATCH_BLOCKS): patches gather, ONE float4 per thread.
//    Consecutive lanes -> consecutive output float4s, so each wave store
//    instruction covers 1KB contiguous (full 64B lines) -> nontemporal is
//    safe (no partial-line RMW) and keeps 195MB of streaming writes out of
//    L2 so the input stays cache-resident.
//  blocks [PATCH_BLOCKS, +PE_BLOCKS): one thread per (b,n) -> positions +
//    8-NN edges. Regular (cached) stores: the interleaved 16B@32B-stride
//    pattern relies on L2 write-back merging; total is only ~4MB.
// ---------------------------------------------------------------------------
__global__ __launch_bounds__(256) void fused_kernel(const float* __restrict__ x,
                                                    float* __restrict__ out) {
    unsigned bid = blockIdx.x;

    if (bid < PATCH_BLOCKS) {
        unsigned g    = bid * 256u + threadIdx.x;   // [0, TOTAL_G)
        unsigned f4i  = g % F4;
        unsigned rest = g / F4;
        unsigned n    = rest % NN;
        unsigned b    = rest / NN;

        unsigned f  = f4i << 2;             // first feature of the 4
        unsigned c  = f >> 8;               // / 256
        unsigned di = (f >> 4) & 15;
        unsigned dj = f & 15;               // multiple of 4
        unsigned i  = n / NW;
        unsigned j  = n - i * NW;

        const f4 v = *reinterpret_cast<const f4*>(
            x + ((size_t)((b * CH + c) * HH + i * 8u + di) * WW + j * 8u + dj));
        __builtin_nontemporal_store(v, reinterpret_cast<f4*>(out + (size_t)g * 4));
    } else {
        unsigned g = (bid - PATCH_BLOCKS) * 256u + threadIdx.x;
        if (g >= PE_THREADS) return;
        unsigned n = g % NN;                // lanes contiguous in n
        unsigned b = g / NN;
        int i = (int)(n / NW);
        int j = (int)(n - (unsigned)i * NW);

        // positions
        *reinterpret_cast<f2*>(out + PATCHES_ELEMS + (size_t)(b * NN + n) * 2) =
            f2{(float)i, (float)j};

        // 8-NN on the 63x63 grid: the 9 best (incl. self) of top_k(-d2, 9)
        // always lie in the clipped 5x5 window; key = (d2<<12)|idx reproduces
        // top_k's exact ordering (ties -> lower index).
        unsigned best[9];
#pragma unroll
        for (int s = 0; s < 9; ++s) best[s] = 0xFFFFFFFFu;
        for (int di = -2; di <= 2; ++di) {
            int ni = i + di;
            if (ni < 0 || ni >= NH) continue;
            for (int dj = -2; dj <= 2; ++dj) {
                int nj = j + dj;
                if (nj < 0 || nj >= NW) continue;
                unsigned key = ((unsigned)(di * di + dj * dj) << 12)
                             | (unsigned)(ni * NW + nj);
#pragma unroll
                for (int s = 0; s < 9; ++s) {
                    if (key < best[s]) { unsigned tmp = best[s]; best[s] = key; key = tmp; }
                }
            }
        }

        float src_f = (float)n;
        f4 s4 = {src_f, src_f, src_f, src_f};
        f4 t0 = {(float)(best[1] & 0xFFFu), (float)(best[2] & 0xFFFu),
                 (float)(best[3] & 0xFFFu), (float)(best[4] & 0xFFFu)};
        f4 t1 = {(float)(best[5] & 0xFFFu), (float)(best[6] & 0xFFFu),
                 (float)(best[7] & 0xFFFu), (float)(best[8] & 0xFFFu)};

        float* ebase = out + PATCHES_ELEMS + POS_ELEMS + (size_t)b * 2 * EDGES;
        *reinterpret_cast<f4*>(ebase + (size_t)n * 8)             = s4;
        *reinterpret_cast<f4*>(ebase + (size_t)n * 8 + 4)         = s4;
        *reinterpret_cast<f4*>(ebase + EDGES + (size_t)n * 8)     = t0;
        *reinterpret_cast<f4*>(ebase + EDGES + (size_t)n * 8 + 4) = t1;
    }
}

extern "C" void kernel_launch(void* const* d_in, const int* in_sizes, int n_in,
                              void* d_out, int out_size, void* d_ws, size_t ws_size,
                              hipStream_t stream) {
    const float* x = (const float*)d_in[0];
    float* out     = (float*)d_out;
    fused_kernel<<<PATCH_BLOCKS + PE_BLOCKS, 256, 0, stream>>>(x, out);
}